// Round 8
// baseline (5208.313 us; speedup 1.0000x reference)
//
#include <hip/hip_runtime.h>
#include <hip/hip_bf16.h>
#include <stdint.h>

// RAN forward: T=512, B=64, F=512, H=1024 — single fused persistent kernel.
// 256 blocks x 512 thr (grid == CU count, 1 block/CU, all co-resident).
// Group g = XCD-pair owns batches [16g,16g+16); member m owns H-cols
// [16m,16m+16). Per step: 8 waves split K; hh partials (K=1024) accumulate
// onto ih partials precomputed for this t in the PREVIOUS step's barrier
// shadow (ih depends only on X + W_ih registers, not on the barrier).
// bf16x3 split precision; LDS reduce; fp32 h store (agent-scope, to LLC);
// group barrier via measured-safe atomicAdd flags (m20) + acquire fence.
// Weights fp32 -> bf16 hi/lo once per block in the prologue, live in VGPRs.

#define T_STEPS 512
#define NBATCH  64
#define HDIM    1024

typedef __attribute__((ext_vector_type(8))) short short8;
typedef __attribute__((ext_vector_type(4))) float f32x4;

__device__ inline unsigned short f2bf(float x) {
  union { float f; unsigned u; } v; v.f = x;
  unsigned r = v.u + 0x7fffu + ((v.u >> 16) & 1u);  // RNE
  return (unsigned short)(r >> 16);
}
__device__ inline float bf2f(unsigned short b) {
  union { float f; unsigned u; } v; v.u = ((unsigned)b) << 16;
  return v.f;
}
// split 8 fp32 (two f32x4) into bf16 hi/lo fragments
__device__ inline void split8(const f32x4& v0, const f32x4& v1, short8& hi, short8& lo) {
#pragma unroll
  for (int j = 0; j < 4; ++j) {
    unsigned short h1 = f2bf(v0[j]);
    hi[j] = (short)h1;
    lo[j] = (short)f2bf(v0[j] - bf2f(h1));
    unsigned short h2 = f2bf(v1[j]);
    hi[4 + j] = (short)h2;
    lo[4 + j] = (short)f2bf(v1[j] - bf2f(h2));
  }
}

// ---------------- fused RAN kernel ----------------
__global__ __launch_bounds__(512, 2)
void k_ran(const float* __restrict__ X,
           const float* __restrict__ Wih, const float* __restrict__ Whh,
           float* __restrict__ hS,
           const float* __restrict__ bias_ih, const float* __restrict__ bias_hh,
           float* __restrict__ out, unsigned int* __restrict__ flags) {
  const int tid  = threadIdx.x;
  const int lane = tid & 63;
  const int w    = tid >> 6;
  const int B    = blockIdx.x;
  const int g    = (B & 7) >> 1;                 // XCD-pair group (locality heuristic)
  const int m    = ((B >> 3) << 1) | (B & 1);    // member 0..63 (bijective)
  const int c0   = m * 16;

  // [wave][batch16][col16] float4{sum_i,sum_f,sum_n,pad}; stride 17 rows.
  __shared__ f32x4 part[8 * 16 * 17];   // 34816 B

  const int rl = lane & 15;
  const int kq = lane >> 4;             // 0..3 (k-subchunk of 8)

  // --- prologue: load + split weights into registers (one-time) ---
  short8 wfh[2][4][2];                  // W_hh [gate i/f][kk<4][hi/lo], K-slice w*128..+128
  {
    int kb = w * 128 + kq * 8;
#pragma unroll
    for (int nt = 0; nt < 2; ++nt) {
      const float* rp = Whh + (size_t)(nt * 1024 + c0 + rl) * 1024 + kb;
#pragma unroll
      for (int kk = 0; kk < 4; ++kk)
        split8(*(const f32x4*)(rp + kk * 32), *(const f32x4*)(rp + kk * 32 + 4),
               wfh[nt][kk][0], wfh[nt][kk][1]);
    }
  }
  short8 wfx[3][2][2];                  // W_ih [gate i/f/n][kk<2][hi/lo], K-slice w*64..+64
  {
    int kb = w * 64 + kq * 8;
#pragma unroll
    for (int nt = 0; nt < 3; ++nt) {
      const float* rp = Wih + (size_t)(nt * 1024 + c0 + rl) * 512 + kb;
#pragma unroll
      for (int kk = 0; kk < 2; ++kk)
        split8(*(const f32x4*)(rp + kk * 32), *(const f32x4*)(rp + kk * 32 + 4),
               wfx[nt][kk][0], wfx[nt][kk][1]);
    }
  }

  // --- epilogue-thread constants (threads 0..255 own one (b,c) element) ---
  const int eb  = tid >> 4;
  const int ec  = tid & 15;
  const int ebg = g * 16 + eb;
  const int ecg = c0 + ec;
  float b_ii = 0.f, b_if = 0.f, b_in = 0.f, b_hi = 0.f, b_hf = 0.f;
  float hreg = 0.f;
  if (tid < 256) {
    b_ii = bias_ih[ecg];
    b_if = bias_ih[1024 + ecg];
    b_in = bias_ih[2048 + ecg];
    b_hi = bias_hh[ecg];
    b_hf = bias_hh[1024 + ecg];
  }

  const int    abg   = g * 16 + rl;     // A-frag batch row (all waves)
  const size_t hbase = (size_t)abg * HDIM + (size_t)(w * 128 + kq * 8);
  const size_t xbase = (size_t)abg * 512  + (size_t)(w * 64  + kq * 8);

  // ih-partial pass over xv registers into acc (bf16x3)
  f32x4 acc0, acc1, acc2;
  f32x4 xv[4];
  auto ih_pass = [&]() {
#pragma unroll
    for (int kk = 0; kk < 2; ++kk) {
      short8 ahi, alo;
      split8(xv[kk * 2], xv[kk * 2 + 1], ahi, alo);
      acc0 = __builtin_amdgcn_mfma_f32_16x16x32_bf16(ahi, wfx[0][kk][0], acc0, 0, 0, 0);
      acc0 = __builtin_amdgcn_mfma_f32_16x16x32_bf16(ahi, wfx[0][kk][1], acc0, 0, 0, 0);
      acc0 = __builtin_amdgcn_mfma_f32_16x16x32_bf16(alo, wfx[0][kk][0], acc0, 0, 0, 0);
      acc1 = __builtin_amdgcn_mfma_f32_16x16x32_bf16(ahi, wfx[1][kk][0], acc1, 0, 0, 0);
      acc1 = __builtin_amdgcn_mfma_f32_16x16x32_bf16(ahi, wfx[1][kk][1], acc1, 0, 0, 0);
      acc1 = __builtin_amdgcn_mfma_f32_16x16x32_bf16(alo, wfx[1][kk][0], acc1, 0, 0, 0);
      acc2 = __builtin_amdgcn_mfma_f32_16x16x32_bf16(ahi, wfx[2][kk][0], acc2, 0, 0, 0);
      acc2 = __builtin_amdgcn_mfma_f32_16x16x32_bf16(ahi, wfx[2][kk][1], acc2, 0, 0, 0);
      acc2 = __builtin_amdgcn_mfma_f32_16x16x32_bf16(alo, wfx[2][kk][0], acc2, 0, 0, 0);
    }
  };

  // X(0) prefetch + ih partials for t=0
#pragma unroll
  for (int kk = 0; kk < 2; ++kk) {
    xv[kk * 2]     = *(const f32x4*)(X + xbase + kk * 32);
    xv[kk * 2 + 1] = *(const f32x4*)(X + xbase + kk * 32 + 4);
  }
  acc0 = f32x4{}; acc1 = f32x4{}; acc2 = f32x4{};
  ih_pass();

  for (int t = 0; t < T_STEPS; ++t) {
    const int curoff = (t & 1) * (NBATCH * HDIM);
    const int nxtoff = ((t & 1) ^ 1) * (NBATCH * HDIM);

    // --- 1. issue h(t) loads first (LLC latency on critical path), then
    //     X(t+1) loads (consumed ~2500cy later in the shadow) ---
    f32x4 hv[8];
#pragma unroll
    for (int kk = 0; kk < 4; ++kk) {
      const float* hp = hS + (size_t)curoff + hbase + kk * 32;
      hv[kk * 2]     = *(const f32x4*)(hp);
      hv[kk * 2 + 1] = *(const f32x4*)(hp + 4);
    }
    {
      int tn = (t + 1 < T_STEPS) ? (t + 1) : t;
      const float* xp0 = X + (size_t)tn * (NBATCH * 512) + xbase;
#pragma unroll
      for (int kk = 0; kk < 2; ++kk) {
        xv[kk * 2]     = *(const f32x4*)(xp0 + kk * 32);
        xv[kk * 2 + 1] = *(const f32x4*)(xp0 + kk * 32 + 4);
      }
    }

    // --- 2. hh partials accumulate onto precomputed ih partials ---
#pragma unroll
    for (int kk = 0; kk < 4; ++kk) {
      short8 ahi, alo;
      split8(hv[kk * 2], hv[kk * 2 + 1], ahi, alo);
      acc0 = __builtin_amdgcn_mfma_f32_16x16x32_bf16(ahi, wfh[0][kk][0], acc0, 0, 0, 0);
      acc0 = __builtin_amdgcn_mfma_f32_16x16x32_bf16(ahi, wfh[0][kk][1], acc0, 0, 0, 0);
      acc0 = __builtin_amdgcn_mfma_f32_16x16x32_bf16(alo, wfh[0][kk][0], acc0, 0, 0, 0);
      acc1 = __builtin_amdgcn_mfma_f32_16x16x32_bf16(ahi, wfh[1][kk][0], acc1, 0, 0, 0);
      acc1 = __builtin_amdgcn_mfma_f32_16x16x32_bf16(ahi, wfh[1][kk][1], acc1, 0, 0, 0);
      acc1 = __builtin_amdgcn_mfma_f32_16x16x32_bf16(alo, wfh[1][kk][0], acc1, 0, 0, 0);
    }
    // D layout (m89): col = lane&15, row(batch) = (lane>>4)*4 + q
#pragma unroll
    for (int q = 0; q < 4; ++q) {
      int b = kq * 4 + q;
      f32x4 e = { acc0[q], acc1[q], acc2[q], 0.f };
      part[(w * 16 + b) * 17 + rl] = e;
    }
    __syncthreads();

    // --- 3. reduce over 8 waves + gate update (threads 0..255) ---
    float hn = 0.f;
    if (tid < 256) {
      float si = 0.f, sf = 0.f, sn = 0.f;
#pragma unroll
      for (int ww = 0; ww < 8; ++ww) {
        f32x4 p = part[(ww * 16 + eb) * 17 + ec];
        si += p[0]; sf += p[1]; sn += p[2];
      }
      float ig = 1.f / (1.f + __expf(-(si + b_ii + b_hi)));
      float fg = 1.f / (1.f + __expf(-(sf + b_if + b_hf)));
      hn = ig * (sn + b_in) + fg * hreg;
      hreg = hn;
      // agent-scope store: straight to the coherent point (LLC)
      __hip_atomic_store(&hS[(size_t)nxtoff + (size_t)ebg * HDIM + ecg], hn,
                         __ATOMIC_RELAXED, __HIP_MEMORY_SCOPE_AGENT);
    }

    // --- 4. arrive: drain stores (syncthreads waits vmcnt), one release
    //     fence, then measured-safe RMW post ---
    __syncthreads();
    if (tid == 0) {
      __threadfence();                              // release duty (L2 writeback)
      atomicAdd(&flags[(g * 64 + m) * 32], 1u);     // flag -> t+1 (m20: device-scope)
    }

    // --- 5. barrier shadow: out write + ih partials for t+1 (X already
    //     in flight since step top; no barrier dependency) ---
    if (tid < 256)
      out[((size_t)t * NBATCH + ebg) * HDIM + ecg] = tanhf(hn);
    acc0 = f32x4{}; acc1 = f32x4{}; acc2 = f32x4{};
    ih_pass();

    // --- 6. wait: wave 0 polls via atomicAdd(+0) (forced coherent read),
    //     then ONE acquire fence (inv, no writeback drain) ---
    if (tid < 64) {
      const unsigned tgt = (unsigned)(t + 1);
      for (;;) {
        unsigned v = atomicAdd(&flags[(g * 64 + tid) * 32], 0u);
        if (__all((int)(v >= tgt))) break;
        __builtin_amdgcn_s_sleep(2);
      }
      __builtin_amdgcn_fence(__ATOMIC_ACQUIRE, "agent");  // invalidate L1/L2
    }
    __syncthreads();
  }
}

// ---------------- launcher ----------------
extern "C" void kernel_launch(void* const* d_in, const int* in_sizes, int n_in,
                              void* d_out, int out_size, void* d_ws, size_t ws_size,
                              hipStream_t stream) {
  const float* x    = (const float*)d_in[0];   // [512,64,512]
  const float* w_ih = (const float*)d_in[1];   // [3072,512]
  const float* w_hh = (const float*)d_in[2];   // [2048,1024]
  const float* b_ih = (const float*)d_in[3];   // [3072]
  const float* b_hh = (const float*)d_in[4];   // [2048]
  float* out = (float*)d_out;

  char* ws = (char*)d_ws;
  float*        h_st  = (float*)(ws);                         // [2][64][1024] fp32, 512KB
  unsigned int* flags = (unsigned int*)(ws + (512ull << 10)); // [256] @128B stride, 32KB

  hipMemsetAsync(h_st, 0, 512 << 10, stream);   // zero both hidden buffers
  hipMemsetAsync(flags, 0, 32 << 10, stream);   // zero barrier flags

  k_ran<<<256, 512, 0, stream>>>(x, w_ih, w_hh, h_st, b_ih, b_hh, out, flags);
}